// Round 10
// baseline (305.878 us; speedup 1.0000x reference)
//
#include <hip/hip_runtime.h>
#include <stdint.h>

typedef __bf16 bf16x8 __attribute__((ext_vector_type(8)));
typedef float f32x4 __attribute__((ext_vector_type(4)));

#define NSAMPLE 64
static constexpr int Bb = 4, Nn = 16384, Mm = 1024, Cc = 256;

__device__ __forceinline__ unsigned short f2bf(float f) {
  unsigned int u = __builtin_bit_cast(unsigned int, f);
  u = u + 0x7fffu + ((u >> 16) & 1u);
  return (unsigned short)(u >> 16);
}

// async global->LDS, 16B per lane; LDS dest = wave-uniform base + lane*16
__device__ __forceinline__ void gload_lds16(const void* g, void* lds) {
  __builtin_amdgcn_global_load_lds(
      (const __attribute__((address_space(1))) uint32_t*)g,
      (__attribute__((address_space(3))) uint32_t*)lds, 16, 0, 0);
}

// ---------------- weight prep: BN fold; W1 split into feature part (bf16) + coord part (f32) ----
__global__ void prep_kernel(const float* __restrict__ W1, const float* __restrict__ b1,
                            const float* __restrict__ g1, const float* __restrict__ be1,
                            const float* __restrict__ m1, const float* __restrict__ v1,
                            const float* __restrict__ W2, const float* __restrict__ b2,
                            const float* __restrict__ g2, const float* __restrict__ be2,
                            const float* __restrict__ m2, const float* __restrict__ v2,
                            unsigned short* __restrict__ W1b, float* __restrict__ w1c,
                            float* __restrict__ b1e,
                            unsigned short* __restrict__ W2b, float* __restrict__ b2e) {
  int t = blockIdx.x * 256 + threadIdx.x;
  if (t < 256 * 256) {
    int o = t >> 8, k = t & 255;
    float s1 = g1[o] / sqrtf(v1[o] + 1e-5f);
    W1b[t] = f2bf(W1[o * 259 + 3 + k] * s1);   // feature cols 3..258 -> k 0..255
    float s2 = g2[o] / sqrtf(v2[o] + 1e-5f);
    W2b[t] = f2bf(W2[t] * s2);
  }
  if (t < 256 * 3) {
    int o = t / 3, c = t - o * 3;
    float s = g1[o] / sqrtf(v1[o] + 1e-5f);
    w1c[t] = W1[o * 259 + c] * s;              // coord cols 0..2, kept f32
  }
  if (t < 256) {
    float s1 = g1[t] / sqrtf(v1[t] + 1e-5f);
    b1e[t] = s1 * (b1[t] - m1[t]) + be1[t];
    float s2 = g2[t] / sqrtf(v2[t] + 1e-5f);
    b2e[t] = s2 * (b2[t] - m2[t]) + be2[t];
  }
}

// ---------------- xyz -> float4 (x,y,z,|p|^2) — R1 verbatim ----------------
__global__ void xyzw_kernel(const float* __restrict__ xyz, float4* __restrict__ xyzw) {
  int t = blockIdx.x * 256 + threadIdx.x;
  float x = xyz[t * 3], y = xyz[t * 3 + 1], z = xyz[t * 3 + 2];
  float pp = __fadd_rn(__fadd_rn(__fmul_rn(x, x), __fmul_rn(y, y)), __fmul_rn(z, z));
  xyzw[t] = make_float4(x, y, z, pp);
}

// ---------------- feats [B,C,N] f32 -> featsT [B,N,C] bf16; ushort4 writes — R8 verbatim -------
__global__ void featsT_kernel(const float* __restrict__ feats, unsigned short* __restrict__ featsT) {
  __shared__ float tile[64][65];
  int bx = blockIdx.x;            // 4*256*4 = 4096
  int b = bx >> 10;
  int rem = bx & 1023;
  int nt = rem >> 2, ct = rem & 3;
  int t = threadIdx.x, tx = t & 63, ty = t >> 6;
  const float* src = feats + ((size_t)b * Cc + ct * 64) * Nn + nt * 64;
#pragma unroll
  for (int i = 0; i < 16; i++) {
    int c = i * 4 + ty;
    tile[c][tx] = src[(size_t)c * Nn + tx];
  }
  __syncthreads();
  unsigned short* dst = featsT + ((size_t)b * Nn + nt * 64) * Cc + ct * 64;
  int c4 = (t & 15) * 4, n0 = t >> 4;
#pragma unroll
  for (int i = 0; i < 4; i++) {
    int n = i * 16 + n0;
    ushort4 v;
    v.x = f2bf(tile[c4][n]);
    v.y = f2bf(tile[c4 + 1][n]);
    v.z = f2bf(tile[c4 + 2][n]);
    v.w = f2bf(tile[c4 + 3][n]);
    *(ushort4*)&dst[(size_t)n * Cc + c4] = v;
  }
}

// ---------------- ball query — R1 verbatim ----------------
__global__ void ballq_kernel(const float4* __restrict__ xyzw, const float* __restrict__ new_xyz,
                             int* __restrict__ idx) {
  const float r2 = (float)(0.08 * 0.08);
  int bm = blockIdx.x * 4 + (threadIdx.x >> 6);
  int lane = threadIdx.x & 63;
  int b = bm >> 10;
  float qx = new_xyz[bm * 3], qy = new_xyz[bm * 3 + 1], qz = new_xyz[bm * 3 + 2];
  float qq = __fadd_rn(__fadd_rn(__fmul_rn(qx, qx), __fmul_rn(qy, qy)), __fmul_rn(qz, qz));
  const float4* P = xyzw + (size_t)b * Nn;
  int* out = idx + (size_t)bm * NSAMPLE;
  int cnt = 0, first = 0;
  bool havef = false;
  for (int n0 = 0; n0 < Nn; n0 += 64) {
    float4 p = P[n0 + lane];
    float dt = __fadd_rn(__fadd_rn(__fmul_rn(qx, p.x), __fmul_rn(qy, p.y)), __fmul_rn(qz, p.z));
    float d2 = __fsub_rn(__fadd_rn(qq, p.w), __fmul_rn(2.f, dt));
    bool valid = d2 < r2;
    unsigned long long mask = __ballot(valid);
    if (mask) {
      if (!havef) { first = n0 + __builtin_ctzll(mask); havef = true; }
      if (valid) {
        int pos = cnt + __popcll(mask & ((1ull << lane) - 1ull));
        if (pos < NSAMPLE) out[pos] = n0 + lane;
      }
      cnt += (int)__popcll(mask);
      if (cnt >= NSAMPLE) break;
    }
  }
  int cc = cnt < NSAMPLE ? cnt : NSAMPLE;
  if (lane >= cc) out[lane] = havef ? first : 0;
}

// ---------------- fused: 1 query/block (zero cross-query state), 33.5KB LDS, 4 blocks/CU ------
// Xf[64][256] bf16 linear; element (r, chunk c) stored at LDS chunk c^(r&7); gather applies the
// inverse on the GLOBAL chunk (rule #21). H aliases Xf after B3. Xc[3][64]: rel coords, written
// in prologue, broadcast-read in epi-1 (16 lanes share a row -> conflict-free).
// Register discipline (R6/R7/R9 lesson): NO persistent arrays besides acc (AGPR); bias/BN scalars
// loaded transiently inside epilogues. Target VGPR+AGPR <= ~140.
__global__ __launch_bounds__(256) void fused_kernel(
    const unsigned short* __restrict__ featsT, const float4* __restrict__ xyzw,
    const float* __restrict__ new_xyz, const int* __restrict__ idx,
    const unsigned short* __restrict__ W1b, const float* __restrict__ w1c,
    const float* __restrict__ b1e,
    const unsigned short* __restrict__ W2b, const float* __restrict__ b2e,
    float* __restrict__ out) {
  __shared__ unsigned short Xf[64 * 256];  // 32768 B
  __shared__ float Xc[3][64];              // 768 B
  int t = threadIdx.x;
  int wave = t >> 6, lane = t & 63;
  int lr = lane & 15, kg = lane >> 4;
  int wcol = wave * 64;
  int bm = blockIdx.x;
  int b = bm >> 10;

  // ---- prologue: coords + async gather ----
  if (t < 64) {
    int ci = idx[(size_t)bm * NSAMPLE + t];
    float4 p = xyzw[(size_t)b * Nn + ci];
    Xc[0][t] = p.x - new_xyz[bm * 3];
    Xc[1][t] = p.y - new_xyz[bm * 3 + 1];
    Xc[2][t] = p.z - new_xyz[bm * 3 + 2];
  }
  {
    int idxr = idx[(size_t)bm * NSAMPLE + wave * 16 + (lane & 15)];
#pragma unroll
    for (int i = 0; i < 8; i++) {
      int j = wave * 8 + i;                       // row pair 2j, 2j+1
      int iv = __shfl(idxr, 2 * i + (lane >> 5));
      int r7 = (2 * j + (lane >> 5)) & 7;
      int cg = (lane & 31) ^ r7;                  // swizzled global chunk
      gload_lds16(featsT + ((size_t)b * Nn + iv) * Cc + cg * 8, &Xf[j * 512]);
    }
  }
  __syncthreads();

  // ---- layer 1: [64x256]x[256x256], W1 streamed from L2, swizzled LDS reads ----
  f32x4 acc[4][4];
#pragma unroll
  for (int mi = 0; mi < 4; mi++)
#pragma unroll
    for (int ni = 0; ni < 4; ni++) acc[mi][ni] = (f32x4){0.f, 0.f, 0.f, 0.f};
#pragma unroll
  for (int kk = 0; kk < 8; kk++) {
    bf16x8 w[4];
#pragma unroll
    for (int ni = 0; ni < 4; ni++)
      w[ni] = *(const bf16x8*)&W1b[(size_t)(wcol + ni * 16 + lr) * 256 + kk * 32 + kg * 8];
#pragma unroll
    for (int mi = 0; mi < 4; mi++) {
      int r = mi * 16 + lr;
      int cs = ((kk * 4 + kg) ^ (r & 7)) * 8;
      bf16x8 a = *(const bf16x8*)&Xf[r * 256 + cs];
#pragma unroll
      for (int ni = 0; ni < 4; ni++)
        acc[mi][ni] = __builtin_amdgcn_mfma_f32_16x16x32_bf16(a, w[ni], acc[mi][ni], 0, 0, 0);
    }
  }
  __syncthreads();  // B3: all waves done reading Xf (X1 view)

  // ---- epilogue 1: bias + coord term (Xc broadcast) + relu -> H (aliases Xf, swizzled) ----
#pragma unroll
  for (int ni = 0; ni < 4; ni++) {
    int o = wcol + ni * 16 + lr;
    float bb = b1e[o];
    float wx = w1c[o * 3], wy = w1c[o * 3 + 1], wz = w1c[o * 3 + 2];
#pragma unroll
    for (int mi = 0; mi < 4; mi++)
#pragma unroll
      for (int j = 0; j < 4; j++) {
        int r = mi * 16 + kg * 4 + j;
        float h = acc[mi][ni][j] + bb + Xc[0][r] * wx + Xc[1][r] * wy + Xc[2][r] * wz;
        h = fmaxf(h, 0.f);
        Xf[r * 256 + ((((o >> 3) ^ (r & 7)) << 3) + (o & 7))] = f2bf(h);
      }
  }
  __syncthreads();  // B4: H visible

  // ---- layer 2: [64x256]x[256x256] from H (same swizzle) ----
#pragma unroll
  for (int mi = 0; mi < 4; mi++)
#pragma unroll
    for (int ni = 0; ni < 4; ni++) acc[mi][ni] = (f32x4){0.f, 0.f, 0.f, 0.f};
#pragma unroll
  for (int kk = 0; kk < 8; kk++) {
    bf16x8 w[4];
#pragma unroll
    for (int ni = 0; ni < 4; ni++)
      w[ni] = *(const bf16x8*)&W2b[(size_t)(wcol + ni * 16 + lr) * 256 + kk * 32 + kg * 8];
#pragma unroll
    for (int mi = 0; mi < 4; mi++) {
      int r = mi * 16 + lr;
      int cs = ((kk * 4 + kg) ^ (r & 7)) * 8;
      bf16x8 a = *(const bf16x8*)&Xf[r * 256 + cs];
#pragma unroll
      for (int ni = 0; ni < 4; ni++)
        acc[mi][ni] = __builtin_amdgcn_mfma_f32_16x16x32_bf16(a, w[ni], acc[mi][ni], 0, 0, 0);
    }
  }
  // ---- epilogue 2: bias + relu + max over 64 samples -> out[b][o][m] ----
  {
    int m = bm & (Mm - 1);
#pragma unroll
    for (int ni = 0; ni < 4; ni++) {
      float bv = b2e[wcol + ni * 16 + lr];
      float v = 0.f;  // relu(max) == max(relu)
#pragma unroll
      for (int mi = 0; mi < 4; mi++)
#pragma unroll
        for (int j = 0; j < 4; j++) v = fmaxf(v, acc[mi][ni][j] + bv);
      v = fmaxf(v, __shfl_xor(v, 16));
      v = fmaxf(v, __shfl_xor(v, 32));
      if (kg == 0)
        out[((size_t)b * 256 + wcol + ni * 16 + lr) * Mm + m] = v;
    }
  }
}

extern "C" void kernel_launch(void* const* d_in, const int* in_sizes, int n_in,
                              void* d_out, int out_size, void* d_ws, size_t ws_size,
                              hipStream_t stream) {
  (void)in_sizes; (void)n_in; (void)out_size; (void)ws_size;
  const float* xyz     = (const float*)d_in[0];
  const float* new_xyz = (const float*)d_in[1];
  const float* feats   = (const float*)d_in[2];
  const float* W1 = (const float*)d_in[3];
  const float* b1 = (const float*)d_in[4];
  const float* g1 = (const float*)d_in[5];
  const float* be1 = (const float*)d_in[6];
  const float* m1 = (const float*)d_in[7];
  const float* v1 = (const float*)d_in[8];
  const float* W2 = (const float*)d_in[9];
  const float* b2 = (const float*)d_in[10];
  const float* g2 = (const float*)d_in[11];
  const float* be2 = (const float*)d_in[12];
  const float* m2 = (const float*)d_in[13];
  const float* v2 = (const float*)d_in[14];
  float* out = (float*)d_out;

  char* ws = (char*)d_ws;
  unsigned short* W1b   = (unsigned short*)(ws + 0);         // 131072 B
  unsigned short* W2b   = (unsigned short*)(ws + 131072);    // 131072 B
  float*          w1c   = (float*)(ws + 262144);             // 3072 B
  float*          b1e   = (float*)(ws + 265216);             // 1024 B
  float*          b2e   = (float*)(ws + 266240);             // 1024 B
  float4*         xyzw  = (float4*)(ws + 267264);            // 1048576 B
  unsigned short* featsT= (unsigned short*)(ws + 1315840);   // 33554432 B
  int*            idx   = (int*)(ws + 34870272);             // 1048576 B (end ~35.9 MB)

  prep_kernel<<<256, 256, 0, stream>>>(
      W1, b1, g1, be1, m1, v1, W2, b2, g2, be2, m2, v2, W1b, w1c, b1e, W2b, b2e);
  xyzw_kernel<<<(Bb * Nn) / 256, 256, 0, stream>>>(xyz, xyzw);
  featsT_kernel<<<Bb * (Nn / 64) * (Cc / 64), 256, 0, stream>>>(feats, featsT);
  ballq_kernel<<<(Bb * Mm) / 4, 256, 0, stream>>>(xyzw, new_xyz, idx);
  fused_kernel<<<Bb * Mm, 256, 0, stream>>>(featsT, xyzw, new_xyz, idx,
                                            W1b, w1c, b1e, W2b, b2e, out);
}

// Round 11
// 297.602 us; speedup vs baseline: 1.0278x; 1.0278x over previous
//
#include <hip/hip_runtime.h>
#include <stdint.h>

typedef __bf16 bf16x8 __attribute__((ext_vector_type(8)));
typedef float f32x4 __attribute__((ext_vector_type(4)));

#define NSAMPLE 64
static constexpr int Bb = 4, Nn = 16384, Mm = 1024, Cc = 256;

__device__ __forceinline__ unsigned short f2bf(float f) {
  unsigned int u = __builtin_bit_cast(unsigned int, f);
  u = u + 0x7fffu + ((u >> 16) & 1u);
  return (unsigned short)(u >> 16);
}

// async global->LDS, 16B per lane; LDS dest = wave-uniform base + lane*16
__device__ __forceinline__ void gload_lds16(const void* g, void* lds) {
  __builtin_amdgcn_global_load_lds(
      (const __attribute__((address_space(1))) uint32_t*)g,
      (__attribute__((address_space(3))) uint32_t*)lds, 16, 0, 0);
}

// ---------------- weight prep: BN fold; W1 split into feature part (bf16) + coord part (f32) ----
__global__ void prep_kernel(const float* __restrict__ W1, const float* __restrict__ b1,
                            const float* __restrict__ g1, const float* __restrict__ be1,
                            const float* __restrict__ m1, const float* __restrict__ v1,
                            const float* __restrict__ W2, const float* __restrict__ b2,
                            const float* __restrict__ g2, const float* __restrict__ be2,
                            const float* __restrict__ m2, const float* __restrict__ v2,
                            unsigned short* __restrict__ W1b, float* __restrict__ w1c,
                            float* __restrict__ b1e,
                            unsigned short* __restrict__ W2b, float* __restrict__ b2e) {
  int t = blockIdx.x * 256 + threadIdx.x;
  if (t < 256 * 256) {
    int o = t >> 8, k = t & 255;
    float s1 = g1[o] / sqrtf(v1[o] + 1e-5f);
    W1b[t] = f2bf(W1[o * 259 + 3 + k] * s1);   // feature cols 3..258 -> k 0..255
    float s2 = g2[o] / sqrtf(v2[o] + 1e-5f);
    W2b[t] = f2bf(W2[t] * s2);
  }
  if (t < 256 * 3) {
    int o = t / 3, c = t - o * 3;
    float s = g1[o] / sqrtf(v1[o] + 1e-5f);
    w1c[t] = W1[o * 259 + c] * s;              // coord cols 0..2, kept f32
  }
  if (t < 256) {
    float s1 = g1[t] / sqrtf(v1[t] + 1e-5f);
    b1e[t] = s1 * (b1[t] - m1[t]) + be1[t];
    float s2 = g2[t] / sqrtf(v2[t] + 1e-5f);
    b2e[t] = s2 * (b2[t] - m2[t]) + be2[t];
  }
}

// ---------------- xyz -> float4 (x,y,z,|p|^2) — R1 verbatim ----------------
__global__ void xyzw_kernel(const float* __restrict__ xyz, float4* __restrict__ xyzw) {
  int t = blockIdx.x * 256 + threadIdx.x;
  float x = xyz[t * 3], y = xyz[t * 3 + 1], z = xyz[t * 3 + 2];
  float pp = __fadd_rn(__fadd_rn(__fmul_rn(x, x), __fmul_rn(y, y)), __fmul_rn(z, z));
  xyzw[t] = make_float4(x, y, z, pp);
}

// ---------------- feats [B,C,N] f32 -> featsT [B,N,C] bf16; ushort4 writes — R8 verbatim -------
__global__ void featsT_kernel(const float* __restrict__ feats, unsigned short* __restrict__ featsT) {
  __shared__ float tile[64][65];
  int bx = blockIdx.x;            // 4*256*4 = 4096
  int b = bx >> 10;
  int rem = bx & 1023;
  int nt = rem >> 2, ct = rem & 3;
  int t = threadIdx.x, tx = t & 63, ty = t >> 6;
  const float* src = feats + ((size_t)b * Cc + ct * 64) * Nn + nt * 64;
#pragma unroll
  for (int i = 0; i < 16; i++) {
    int c = i * 4 + ty;
    tile[c][tx] = src[(size_t)c * Nn + tx];
  }
  __syncthreads();
  unsigned short* dst = featsT + ((size_t)b * Nn + nt * 64) * Cc + ct * 64;
  int c4 = (t & 15) * 4, n0 = t >> 4;
#pragma unroll
  for (int i = 0; i < 4; i++) {
    int n = i * 16 + n0;
    ushort4 v;
    v.x = f2bf(tile[c4][n]);
    v.y = f2bf(tile[c4 + 1][n]);
    v.z = f2bf(tile[c4 + 2][n]);
    v.w = f2bf(tile[c4 + 3][n]);
    *(ushort4*)&dst[(size_t)n * Cc + c4] = v;
  }
}

// ---------------- ball query — R1 verbatim ----------------
__global__ void ballq_kernel(const float4* __restrict__ xyzw, const float* __restrict__ new_xyz,
                             int* __restrict__ idx) {
  const float r2 = (float)(0.08 * 0.08);
  int bm = blockIdx.x * 4 + (threadIdx.x >> 6);
  int lane = threadIdx.x & 63;
  int b = bm >> 10;
  float qx = new_xyz[bm * 3], qy = new_xyz[bm * 3 + 1], qz = new_xyz[bm * 3 + 2];
  float qq = __fadd_rn(__fadd_rn(__fmul_rn(qx, qx), __fmul_rn(qy, qy)), __fmul_rn(qz, qz));
  const float4* P = xyzw + (size_t)b * Nn;
  int* out = idx + (size_t)bm * NSAMPLE;
  int cnt = 0, first = 0;
  bool havef = false;
  for (int n0 = 0; n0 < Nn; n0 += 64) {
    float4 p = P[n0 + lane];
    float dt = __fadd_rn(__fadd_rn(__fmul_rn(qx, p.x), __fmul_rn(qy, p.y)), __fmul_rn(qz, p.z));
    float d2 = __fsub_rn(__fadd_rn(qq, p.w), __fmul_rn(2.f, dt));
    bool valid = d2 < r2;
    unsigned long long mask = __ballot(valid);
    if (mask) {
      if (!havef) { first = n0 + __builtin_ctzll(mask); havef = true; }
      if (valid) {
        int pos = cnt + __popcll(mask & ((1ull << lane) - 1ull));
        if (pos < NSAMPLE) out[pos] = n0 + lane;
      }
      cnt += (int)__popcll(mask);
      if (cnt >= NSAMPLE) break;
    }
  }
  int cc = cnt < NSAMPLE ? cnt : NSAMPLE;
  if (lane >= cc) out[lane] = havef ? first : 0;
}

// ---------------- fused: R10 body + __launch_bounds__(256,4) => total regs/wave <= 128 ----------
// The ONLY change vs R10: min-waves/EU = 4. R5 proved this structure fits 128 total (64 arch +
// 64 acc) without spilling; R7-R10's occupancy collapse was the compiler's fat schedule when
// no min-wave target was declared. Spill tripwire: FETCH_SIZE must stay ~34 MB.
__global__ __launch_bounds__(256, 4) void fused_kernel(
    const unsigned short* __restrict__ featsT, const float4* __restrict__ xyzw,
    const float* __restrict__ new_xyz, const int* __restrict__ idx,
    const unsigned short* __restrict__ W1b, const float* __restrict__ w1c,
    const float* __restrict__ b1e,
    const unsigned short* __restrict__ W2b, const float* __restrict__ b2e,
    float* __restrict__ out) {
  __shared__ unsigned short Xf[64 * 256];  // 32768 B
  __shared__ float Xc[3][64];              // 768 B
  int t = threadIdx.x;
  int wave = t >> 6, lane = t & 63;
  int lr = lane & 15, kg = lane >> 4;
  int wcol = wave * 64;
  int bm = blockIdx.x;
  int b = bm >> 10;

  // ---- prologue: coords + async gather ----
  if (t < 64) {
    int ci = idx[(size_t)bm * NSAMPLE + t];
    float4 p = xyzw[(size_t)b * Nn + ci];
    Xc[0][t] = p.x - new_xyz[bm * 3];
    Xc[1][t] = p.y - new_xyz[bm * 3 + 1];
    Xc[2][t] = p.z - new_xyz[bm * 3 + 2];
  }
  {
    int idxr = idx[(size_t)bm * NSAMPLE + wave * 16 + (lane & 15)];
#pragma unroll
    for (int i = 0; i < 8; i++) {
      int j = wave * 8 + i;                       // row pair 2j, 2j+1
      int iv = __shfl(idxr, 2 * i + (lane >> 5));
      int r7 = (2 * j + (lane >> 5)) & 7;
      int cg = (lane & 31) ^ r7;                  // swizzled global chunk
      gload_lds16(featsT + ((size_t)b * Nn + iv) * Cc + cg * 8, &Xf[j * 512]);
    }
  }
  __syncthreads();

  // ---- layer 1: [64x256]x[256x256], W1 streamed from L2, swizzled LDS reads ----
  f32x4 acc[4][4];
#pragma unroll
  for (int mi = 0; mi < 4; mi++)
#pragma unroll
    for (int ni = 0; ni < 4; ni++) acc[mi][ni] = (f32x4){0.f, 0.f, 0.f, 0.f};
#pragma unroll
  for (int kk = 0; kk < 8; kk++) {
    bf16x8 w[4];
#pragma unroll
    for (int ni = 0; ni < 4; ni++)
      w[ni] = *(const bf16x8*)&W1b[(size_t)(wcol + ni * 16 + lr) * 256 + kk * 32 + kg * 8];
#pragma unroll
    for (int mi = 0; mi < 4; mi++) {
      int r = mi * 16 + lr;
      int cs = ((kk * 4 + kg) ^ (r & 7)) * 8;
      bf16x8 a = *(const bf16x8*)&Xf[r * 256 + cs];
#pragma unroll
      for (int ni = 0; ni < 4; ni++)
        acc[mi][ni] = __builtin_amdgcn_mfma_f32_16x16x32_bf16(a, w[ni], acc[mi][ni], 0, 0, 0);
    }
  }
  __syncthreads();  // B3: all waves done reading Xf (X1 view)

  // ---- epilogue 1: bias + coord term (Xc broadcast) + relu -> H (aliases Xf, swizzled) ----
#pragma unroll
  for (int ni = 0; ni < 4; ni++) {
    int o = wcol + ni * 16 + lr;
    float bb = b1e[o];
    float wx = w1c[o * 3], wy = w1c[o * 3 + 1], wz = w1c[o * 3 + 2];
#pragma unroll
    for (int mi = 0; mi < 4; mi++)
#pragma unroll
      for (int j = 0; j < 4; j++) {
        int r = mi * 16 + kg * 4 + j;
        float h = acc[mi][ni][j] + bb + Xc[0][r] * wx + Xc[1][r] * wy + Xc[2][r] * wz;
        h = fmaxf(h, 0.f);
        Xf[r * 256 + ((((o >> 3) ^ (r & 7)) << 3) + (o & 7))] = f2bf(h);
      }
  }
  __syncthreads();  // B4: H visible

  // ---- layer 2: [64x256]x[256x256] from H (same swizzle) ----
#pragma unroll
  for (int mi = 0; mi < 4; mi++)
#pragma unroll
    for (int ni = 0; ni < 4; ni++) acc[mi][ni] = (f32x4){0.f, 0.f, 0.f, 0.f};
#pragma unroll
  for (int kk = 0; kk < 8; kk++) {
    bf16x8 w[4];
#pragma unroll
    for (int ni = 0; ni < 4; ni++)
      w[ni] = *(const bf16x8*)&W2b[(size_t)(wcol + ni * 16 + lr) * 256 + kk * 32 + kg * 8];
#pragma unroll
    for (int mi = 0; mi < 4; mi++) {
      int r = mi * 16 + lr;
      int cs = ((kk * 4 + kg) ^ (r & 7)) * 8;
      bf16x8 a = *(const bf16x8*)&Xf[r * 256 + cs];
#pragma unroll
      for (int ni = 0; ni < 4; ni++)
        acc[mi][ni] = __builtin_amdgcn_mfma_f32_16x16x32_bf16(a, w[ni], acc[mi][ni], 0, 0, 0);
    }
  }
  // ---- epilogue 2: bias + relu + max over 64 samples -> out[b][o][m] ----
  {
    int m = bm & (Mm - 1);
#pragma unroll
    for (int ni = 0; ni < 4; ni++) {
      float bv = b2e[wcol + ni * 16 + lr];
      float v = 0.f;  // relu(max) == max(relu)
#pragma unroll
      for (int mi = 0; mi < 4; mi++)
#pragma unroll
        for (int j = 0; j < 4; j++) v = fmaxf(v, acc[mi][ni][j] + bv);
      v = fmaxf(v, __shfl_xor(v, 16));
      v = fmaxf(v, __shfl_xor(v, 32));
      if (kg == 0)
        out[((size_t)b * 256 + wcol + ni * 16 + lr) * Mm + m] = v;
    }
  }
}

extern "C" void kernel_launch(void* const* d_in, const int* in_sizes, int n_in,
                              void* d_out, int out_size, void* d_ws, size_t ws_size,
                              hipStream_t stream) {
  (void)in_sizes; (void)n_in; (void)out_size; (void)ws_size;
  const float* xyz     = (const float*)d_in[0];
  const float* new_xyz = (const float*)d_in[1];
  const float* feats   = (const float*)d_in[2];
  const float* W1 = (const float*)d_in[3];
  const float* b1 = (const float*)d_in[4];
  const float* g1 = (const float*)d_in[5];
  const float* be1 = (const float*)d_in[6];
  const float* m1 = (const float*)d_in[7];
  const float* v1 = (const float*)d_in[8];
  const float* W2 = (const float*)d_in[9];
  const float* b2 = (const float*)d_in[10];
  const float* g2 = (const float*)d_in[11];
  const float* be2 = (const float*)d_in[12];
  const float* m2 = (const float*)d_in[13];
  const float* v2 = (const float*)d_in[14];
  float* out = (float*)d_out;

  char* ws = (char*)d_ws;
  unsigned short* W1b   = (unsigned short*)(ws + 0);         // 131072 B
  unsigned short* W2b   = (unsigned short*)(ws + 131072);    // 131072 B
  float*          w1c   = (float*)(ws + 262144);             // 3072 B
  float*          b1e   = (float*)(ws + 265216);             // 1024 B
  float*          b2e   = (float*)(ws + 266240);             // 1024 B
  float4*         xyzw  = (float4*)(ws + 267264);            // 1048576 B
  unsigned short* featsT= (unsigned short*)(ws + 1315840);   // 33554432 B
  int*            idx   = (int*)(ws + 34870272);             // 1048576 B (end ~35.9 MB)

  prep_kernel<<<256, 256, 0, stream>>>(
      W1, b1, g1, be1, m1, v1, W2, b2, g2, be2, m2, v2, W1b, w1c, b1e, W2b, b2e);
  xyzw_kernel<<<(Bb * Nn) / 256, 256, 0, stream>>>(xyz, xyzw);
  featsT_kernel<<<Bb * (Nn / 64) * (Cc / 64), 256, 0, stream>>>(feats, featsT);
  ballq_kernel<<<(Bb * Mm) / 4, 256, 0, stream>>>(xyzw, new_xyz, idx);
  fused_kernel<<<Bb * Mm, 256, 0, stream>>>(featsT, xyzw, new_xyz, idx,
                                            W1b, w1c, b1e, W2b, b2e, out);
}

// Round 12
// 220.417 us; speedup vs baseline: 1.3877x; 1.3502x over previous
//
#include <hip/hip_runtime.h>
#include <stdint.h>

typedef __bf16 bf16x8 __attribute__((ext_vector_type(8)));
typedef float f32x4 __attribute__((ext_vector_type(4)));

#define NSAMPLE 64
static constexpr int Bb = 4, Nn = 16384, Mm = 1024, Cc = 256;
static constexpr int K1P = 288;   // layer-1 K: 256 features + 3 coords + pad (9 x 32)

__device__ __forceinline__ unsigned short f2bf(float f) {
  unsigned int u = __builtin_bit_cast(unsigned int, f);
  u = u + 0x7fffu + ((u >> 16) & 1u);
  return (unsigned short)(u >> 16);
}

// async global->LDS, 16B per lane; LDS dest = wave-uniform base + lane*16
__device__ __forceinline__ void gload_lds16(const void* g, void* lds) {
  __builtin_amdgcn_global_load_lds(
      (const __attribute__((address_space(1))) uint32_t*)g,
      (__attribute__((address_space(3))) uint32_t*)lds, 16, 0, 0);
}

// ---------------- weight prep: fold BN into W (bf16) and bias (f32) — R1 verbatim ----------------
__global__ void prep_kernel(const float* __restrict__ W1, const float* __restrict__ b1,
                            const float* __restrict__ g1, const float* __restrict__ be1,
                            const float* __restrict__ m1, const float* __restrict__ v1,
                            const float* __restrict__ W2, const float* __restrict__ b2,
                            const float* __restrict__ g2, const float* __restrict__ be2,
                            const float* __restrict__ m2, const float* __restrict__ v2,
                            unsigned short* __restrict__ W1b, float* __restrict__ b1e,
                            unsigned short* __restrict__ W2b, float* __restrict__ b2e) {
  int t = blockIdx.x * 256 + threadIdx.x;
  if (t < 256 * K1P) {
    int o = t / K1P, k = t - o * K1P;
    float s = g1[o] / sqrtf(v1[o] + 1e-5f);
    float w = 0.f;
    if (k < 256) w = W1[o * 259 + 3 + k];        // feature cols
    else if (k < 259) w = W1[o * 259 + (k - 256)];  // coord cols
    W1b[t] = f2bf(w * s);
  }
  if (t < 256 * 256) {
    int o = t >> 8;
    float s = g2[o] / sqrtf(v2[o] + 1e-5f);
    W2b[t] = f2bf(W2[t] * s);
  }
  if (t < 256) {
    float s1 = g1[t] / sqrtf(v1[t] + 1e-5f);
    b1e[t] = s1 * (b1[t] - m1[t]) + be1[t];
    float s2 = g2[t] / sqrtf(v2[t] + 1e-5f);
    b2e[t] = s2 * (b2[t] - m2[t]) + be2[t];
  }
}

// ---------------- xyz -> float4 (x,y,z,|p|^2) — R1 verbatim ----------------
__global__ void xyzw_kernel(const float* __restrict__ xyz, float4* __restrict__ xyzw) {
  int t = blockIdx.x * 256 + threadIdx.x;
  float x = xyz[t * 3], y = xyz[t * 3 + 1], z = xyz[t * 3 + 2];
  float pp = __fadd_rn(__fadd_rn(__fmul_rn(x, x), __fmul_rn(y, y)), __fmul_rn(z, z));
  xyzw[t] = make_float4(x, y, z, pp);
}

// ---------------- feats [B,C,N] f32 -> featsT [B,N,C] bf16; ushort4 writes — R8 verbatim -------
__global__ void featsT_kernel(const float* __restrict__ feats, unsigned short* __restrict__ featsT) {
  __shared__ float tile[64][65];
  int bx = blockIdx.x;            // 4*256*4 = 4096
  int b = bx >> 10;
  int rem = bx & 1023;
  int nt = rem >> 2, ct = rem & 3;
  int t = threadIdx.x, tx = t & 63, ty = t >> 6;
  const float* src = feats + ((size_t)b * Cc + ct * 64) * Nn + nt * 64;
#pragma unroll
  for (int i = 0; i < 16; i++) {
    int c = i * 4 + ty;
    tile[c][tx] = src[(size_t)c * Nn + tx];
  }
  __syncthreads();
  unsigned short* dst = featsT + ((size_t)b * Nn + nt * 64) * Cc + ct * 64;
  int c4 = (t & 15) * 4, n0 = t >> 4;
#pragma unroll
  for (int i = 0; i < 4; i++) {
    int n = i * 16 + n0;
    ushort4 v;
    v.x = f2bf(tile[c4][n]);
    v.y = f2bf(tile[c4 + 1][n]);
    v.z = f2bf(tile[c4 + 2][n]);
    v.w = f2bf(tile[c4 + 3][n]);
    *(ushort4*)&dst[(size_t)n * Cc + c4] = v;
  }
}

// ---------------- ball query — R1 verbatim ----------------
__global__ void ballq_kernel(const float4* __restrict__ xyzw, const float* __restrict__ new_xyz,
                             int* __restrict__ idx) {
  const float r2 = (float)(0.08 * 0.08);
  int bm = blockIdx.x * 4 + (threadIdx.x >> 6);
  int lane = threadIdx.x & 63;
  int b = bm >> 10;
  float qx = new_xyz[bm * 3], qy = new_xyz[bm * 3 + 1], qz = new_xyz[bm * 3 + 2];
  float qq = __fadd_rn(__fadd_rn(__fmul_rn(qx, qx), __fmul_rn(qy, qy)), __fmul_rn(qz, qz));
  const float4* P = xyzw + (size_t)b * Nn;
  int* out = idx + (size_t)bm * NSAMPLE;
  int cnt = 0, first = 0;
  bool havef = false;
  for (int n0 = 0; n0 < Nn; n0 += 64) {
    float4 p = P[n0 + lane];
    float dt = __fadd_rn(__fadd_rn(__fmul_rn(qx, p.x), __fmul_rn(qy, p.y)), __fmul_rn(qz, p.z));
    float d2 = __fsub_rn(__fadd_rn(qq, p.w), __fmul_rn(2.f, dt));
    bool valid = d2 < r2;
    unsigned long long mask = __ballot(valid);
    if (mask) {
      if (!havef) { first = n0 + __builtin_ctzll(mask); havef = true; }
      if (valid) {
        int pos = cnt + __popcll(mask & ((1ull << lane) - 1ull));
        if (pos < NSAMPLE) out[pos] = n0 + lane;
      }
      cnt += (int)__popcll(mask);
      if (cnt >= NSAMPLE) break;
    }
  }
  int cc = cnt < NSAMPLE ? cnt : NSAMPLE;
  if (lane >= cc) out[lane] = havef ? first : 0;
}

// ---------------- fused: R5 register-thin shape + swizzled gload_lds machinery, (256,4) --------
// Coords live as MFMA K-chunk 8 (k 256..287) in a separate Xco[64][40] u16 slab (pad-40 stride:
// rows land on alternating bank octets; Xf rows stay 512B-contiguous for gload_lds). Epilogue-1
// is acc+bias+relu only (the R5 property that fit 64 arch VGPRs). One query/block -> no async in
// flight at barriers -> plain __syncthreads. Spill tripwire: FETCH must be ~35 MB.
__global__ __launch_bounds__(256, 4) void fused_kernel(
    const unsigned short* __restrict__ featsT, const float4* __restrict__ xyzw,
    const float* __restrict__ new_xyz, const int* __restrict__ idx,
    const unsigned short* __restrict__ W1b, const float* __restrict__ b1e,
    const unsigned short* __restrict__ W2b, const float* __restrict__ b2e,
    float* __restrict__ out) {
  __shared__ unsigned short Xf[64 * 256];  // 32768 B, swizzled feature tile / H tile
  __shared__ unsigned short Xco[64 * 40];  // 5120 B, coord K-chunk (3 coords + 29 zeros per row)
  int t = threadIdx.x;
  int wave = t >> 6, lane = t & 63;
  int lr = lane & 15, kg = lane >> 4;
  int wcol = wave * 64;
  int bm = blockIdx.x;
  int b = bm >> 10;

  // ---- prologue: coord rows + async swizzled gather ----
  if (t < 64) {
    int ci = idx[(size_t)bm * NSAMPLE + t];
    float4 p = xyzw[(size_t)b * Nn + ci];
    unsigned int c01 = (unsigned int)f2bf(p.x - new_xyz[bm * 3])
                     | ((unsigned int)f2bf(p.y - new_xyz[bm * 3 + 1]) << 16);
    unsigned int c2 = (unsigned int)f2bf(p.z - new_xyz[bm * 3 + 2]);
    uint4 v0 = make_uint4(c01, c2, 0u, 0u);
    uint4 z = make_uint4(0u, 0u, 0u, 0u);
    uint4* row = (uint4*)&Xco[t * 40];
    row[0] = v0; row[1] = z; row[2] = z; row[3] = z; row[4] = z;
  }
  {
    int idxr = idx[(size_t)bm * NSAMPLE + wave * 16 + (lane & 15)];
#pragma unroll
    for (int i = 0; i < 8; i++) {
      int j = wave * 8 + i;                       // row pair 2j, 2j+1
      int iv = __shfl(idxr, 2 * i + (lane >> 5));
      int r7 = (2 * j + (lane >> 5)) & 7;
      int cg = (lane & 31) ^ r7;                  // swizzled global chunk (rule #21)
      gload_lds16(featsT + ((size_t)b * Nn + iv) * Cc + cg * 8, &Xf[j * 512]);
    }
  }
  __syncthreads();

  // ---- layer 1: [64x288]x[288x256]; kk 0..7 from Xf (swizzled), kk 8 from Xco ----
  f32x4 acc[4][4];
#pragma unroll
  for (int mi = 0; mi < 4; mi++)
#pragma unroll
    for (int ni = 0; ni < 4; ni++) acc[mi][ni] = (f32x4){0.f, 0.f, 0.f, 0.f};
#pragma unroll
  for (int kk = 0; kk < 9; kk++) {
    bf16x8 w[4];
#pragma unroll
    for (int ni = 0; ni < 4; ni++)
      w[ni] = *(const bf16x8*)&W1b[(size_t)(wcol + ni * 16 + lr) * K1P + kk * 32 + kg * 8];
#pragma unroll
    for (int mi = 0; mi < 4; mi++) {
      int r = mi * 16 + lr;
      bf16x8 a;
      if (kk < 8) {
        int cs = ((kk * 4 + kg) ^ (r & 7)) * 8;
        a = *(const bf16x8*)&Xf[r * 256 + cs];
      } else {
        a = *(const bf16x8*)&Xco[r * 40 + kg * 8];
      }
#pragma unroll
      for (int ni = 0; ni < 4; ni++)
        acc[mi][ni] = __builtin_amdgcn_mfma_f32_16x16x32_bf16(a, w[ni], acc[mi][ni], 0, 0, 0);
    }
  }
  __syncthreads();  // B3: all waves done reading Xf

  // ---- epilogue 1 (thin, R5-style): bias + relu -> H (aliases Xf, swizzled store) ----
#pragma unroll
  for (int ni = 0; ni < 4; ni++) {
    int o = wcol + ni * 16 + lr;
    float bb = b1e[o];
#pragma unroll
    for (int mi = 0; mi < 4; mi++)
#pragma unroll
      for (int j = 0; j < 4; j++) {
        int r = mi * 16 + kg * 4 + j;
        float h = fmaxf(acc[mi][ni][j] + bb, 0.f);
        Xf[r * 256 + ((((o >> 3) ^ (r & 7)) << 3) + (o & 7))] = f2bf(h);
      }
  }
  __syncthreads();  // B4: H visible

  // ---- layer 2: [64x256]x[256x256] from H (same swizzle) ----
#pragma unroll
  for (int mi = 0; mi < 4; mi++)
#pragma unroll
    for (int ni = 0; ni < 4; ni++) acc[mi][ni] = (f32x4){0.f, 0.f, 0.f, 0.f};
#pragma unroll
  for (int kk = 0; kk < 8; kk++) {
    bf16x8 w[4];
#pragma unroll
    for (int ni = 0; ni < 4; ni++)
      w[ni] = *(const bf16x8*)&W2b[(size_t)(wcol + ni * 16 + lr) * 256 + kk * 32 + kg * 8];
#pragma unroll
    for (int mi = 0; mi < 4; mi++) {
      int r = mi * 16 + lr;
      int cs = ((kk * 4 + kg) ^ (r & 7)) * 8;
      bf16x8 a = *(const bf16x8*)&Xf[r * 256 + cs];
#pragma unroll
      for (int ni = 0; ni < 4; ni++)
        acc[mi][ni] = __builtin_amdgcn_mfma_f32_16x16x32_bf16(a, w[ni], acc[mi][ni], 0, 0, 0);
    }
  }
  // ---- epilogue 2: bias + relu + max over 64 samples -> out[b][o][m] ----
  {
    int m = bm & (Mm - 1);
#pragma unroll
    for (int ni = 0; ni < 4; ni++) {
      float bv = b2e[wcol + ni * 16 + lr];
      float v = 0.f;  // relu(max) == max(relu)
#pragma unroll
      for (int mi = 0; mi < 4; mi++)
#pragma unroll
        for (int j = 0; j < 4; j++) v = fmaxf(v, acc[mi][ni][j] + bv);
      v = fmaxf(v, __shfl_xor(v, 16));
      v = fmaxf(v, __shfl_xor(v, 32));
      if (kg == 0)
        out[((size_t)b * 256 + wcol + ni * 16 + lr) * Mm + m] = v;
    }
  }
}

extern "C" void kernel_launch(void* const* d_in, const int* in_sizes, int n_in,
                              void* d_out, int out_size, void* d_ws, size_t ws_size,
                              hipStream_t stream) {
  (void)in_sizes; (void)n_in; (void)out_size; (void)ws_size;
  const float* xyz     = (const float*)d_in[0];
  const float* new_xyz = (const float*)d_in[1];
  const float* feats   = (const float*)d_in[2];
  const float* W1 = (const float*)d_in[3];
  const float* b1 = (const float*)d_in[4];
  const float* g1 = (const float*)d_in[5];
  const float* be1 = (const float*)d_in[6];
  const float* m1 = (const float*)d_in[7];
  const float* v1 = (const float*)d_in[8];
  const float* W2 = (const float*)d_in[9];
  const float* b2 = (const float*)d_in[10];
  const float* g2 = (const float*)d_in[11];
  const float* be2 = (const float*)d_in[12];
  const float* m2 = (const float*)d_in[13];
  const float* v2 = (const float*)d_in[14];
  float* out = (float*)d_out;

  char* ws = (char*)d_ws;
  unsigned short* W1b   = (unsigned short*)(ws + 0);         // 147456 B ([256][288])
  unsigned short* W2b   = (unsigned short*)(ws + 147456);    // 131072 B
  float*          b1e   = (float*)(ws + 278528);             // 1024 B
  float*          b2e   = (float*)(ws + 279552);             // 1024 B
  float4*         xyzw  = (float4*)(ws + 280576);            // 1048576 B
  unsigned short* featsT= (unsigned short*)(ws + 1329152);   // 33554432 B
  int*            idx   = (int*)(ws + 34883584);             // 1048576 B

  prep_kernel<<<(256 * K1P + 255) / 256, 256, 0, stream>>>(
      W1, b1, g1, be1, m1, v1, W2, b2, g2, be2, m2, v2, W1b, b1e, W2b, b2e);
  xyzw_kernel<<<(Bb * Nn) / 256, 256, 0, stream>>>(xyz, xyzw);
  featsT_kernel<<<Bb * (Nn / 64) * (Cc / 64), 256, 0, stream>>>(feats, featsT);
  ballq_kernel<<<(Bb * Mm) / 4, 256, 0, stream>>>(xyzw, new_xyz, idx);
  fused_kernel<<<Bb * Mm, 256, 0, stream>>>(featsT, xyzw, new_xyz, idx,
                                            W1b, b1e, W2b, b2e, out);
}

// Round 13
// 212.272 us; speedup vs baseline: 1.4410x; 1.0384x over previous
//
#include <hip/hip_runtime.h>
#include <stdint.h>

typedef __bf16 bf16x8 __attribute__((ext_vector_type(8)));
typedef float f32x4 __attribute__((ext_vector_type(4)));

#define NSAMPLE 64
static constexpr int Bb = 4, Nn = 16384, Mm = 1024, Cc = 256;
static constexpr int K1P = 288;   // layer-1 K: 256 features + 3 coords + pad (9 x 32)

__device__ __forceinline__ unsigned short f2bf(float f) {
  unsigned int u = __builtin_bit_cast(unsigned int, f);
  u = u + 0x7fffu + ((u >> 16) & 1u);
  return (unsigned short)(u >> 16);
}

// async global->LDS, 16B per lane; LDS dest = wave-uniform base + lane*16
__device__ __forceinline__ void gload_lds16(const void* g, void* lds) {
  __builtin_amdgcn_global_load_lds(
      (const __attribute__((address_space(1))) uint32_t*)g,
      (__attribute__((address_space(3))) uint32_t*)lds, 16, 0, 0);
}

// ---------------- weight prep: fold BN into W (bf16) and bias (f32) — R1 verbatim ----------------
__global__ void prep_kernel(const float* __restrict__ W1, const float* __restrict__ b1,
                            const float* __restrict__ g1, const float* __restrict__ be1,
                            const float* __restrict__ m1, const float* __restrict__ v1,
                            const float* __restrict__ W2, const float* __restrict__ b2,
                            const float* __restrict__ g2, const float* __restrict__ be2,
                            const float* __restrict__ m2, const float* __restrict__ v2,
                            unsigned short* __restrict__ W1b, float* __restrict__ b1e,
                            unsigned short* __restrict__ W2b, float* __restrict__ b2e) {
  int t = blockIdx.x * 256 + threadIdx.x;
  if (t < 256 * K1P) {
    int o = t / K1P, k = t - o * K1P;
    float s = g1[o] / sqrtf(v1[o] + 1e-5f);
    float w = 0.f;
    if (k < 256) w = W1[o * 259 + 3 + k];        // feature cols
    else if (k < 259) w = W1[o * 259 + (k - 256)];  // coord cols
    W1b[t] = f2bf(w * s);
  }
  if (t < 256 * 256) {
    int o = t >> 8;
    float s = g2[o] / sqrtf(v2[o] + 1e-5f);
    W2b[t] = f2bf(W2[t] * s);
  }
  if (t < 256) {
    float s1 = g1[t] / sqrtf(v1[t] + 1e-5f);
    b1e[t] = s1 * (b1[t] - m1[t]) + be1[t];
    float s2 = g2[t] / sqrtf(v2[t] + 1e-5f);
    b2e[t] = s2 * (b2[t] - m2[t]) + be2[t];
  }
}

// ---------------- xyz -> float4 (x,y,z,|p|^2) — R1 verbatim (kept separate; see R2-R5 bug) ----
__global__ void xyzw_kernel(const float* __restrict__ xyz, float4* __restrict__ xyzw) {
  int t = blockIdx.x * 256 + threadIdx.x;
  float x = xyz[t * 3], y = xyz[t * 3 + 1], z = xyz[t * 3 + 2];
  float pp = __fadd_rn(__fadd_rn(__fmul_rn(x, x), __fmul_rn(y, y)), __fmul_rn(z, z));
  xyzw[t] = make_float4(x, y, z, pp);
}

// ---- featsT + ballq, merged at BLOCK level (independent work; overlap latency with BW) ----
// blocks 0..1023: ballq (R1-verbatim body). blocks 1024..5119: featsT (R8-verbatim body).
__global__ void featsT_ballq_kernel(const float* __restrict__ feats,
                                    unsigned short* __restrict__ featsT,
                                    const float4* __restrict__ xyzw,
                                    const float* __restrict__ new_xyz,
                                    int* __restrict__ idx) {
  __shared__ float tile[64][65];
  int bx = blockIdx.x;
  int t = threadIdx.x;
  if (bx < 1024) {
    // ---------------- ball query — R1 verbatim ----------------
    const float r2 = (float)(0.08 * 0.08);
    int bm = bx * 4 + (t >> 6);
    int lane = t & 63;
    int b = bm >> 10;
    float qx = new_xyz[bm * 3], qy = new_xyz[bm * 3 + 1], qz = new_xyz[bm * 3 + 2];
    float qq = __fadd_rn(__fadd_rn(__fmul_rn(qx, qx), __fmul_rn(qy, qy)), __fmul_rn(qz, qz));
    const float4* P = xyzw + (size_t)b * Nn;
    int* out = idx + (size_t)bm * NSAMPLE;
    int cnt = 0, first = 0;
    bool havef = false;
    for (int n0 = 0; n0 < Nn; n0 += 64) {
      float4 p = P[n0 + lane];
      float dt = __fadd_rn(__fadd_rn(__fmul_rn(qx, p.x), __fmul_rn(qy, p.y)), __fmul_rn(qz, p.z));
      float d2 = __fsub_rn(__fadd_rn(qq, p.w), __fmul_rn(2.f, dt));
      bool valid = d2 < r2;
      unsigned long long mask = __ballot(valid);
      if (mask) {
        if (!havef) { first = n0 + __builtin_ctzll(mask); havef = true; }
        if (valid) {
          int pos = cnt + __popcll(mask & ((1ull << lane) - 1ull));
          if (pos < NSAMPLE) out[pos] = n0 + lane;
        }
        cnt += (int)__popcll(mask);
        if (cnt >= NSAMPLE) break;
      }
    }
    int cc = cnt < NSAMPLE ? cnt : NSAMPLE;
    if (lane >= cc) out[lane] = havef ? first : 0;
    return;
  }
  // ---------------- featsT — R8 verbatim body ----------------
  int fb = bx - 1024;             // 0..4095
  int b = fb >> 10;
  int rem = fb & 1023;
  int nt = rem >> 2, ct = rem & 3;
  int tx = t & 63, ty = t >> 6;
  const float* src = feats + ((size_t)b * Cc + ct * 64) * Nn + nt * 64;
#pragma unroll
  for (int i = 0; i < 16; i++) {
    int c = i * 4 + ty;
    tile[c][tx] = src[(size_t)c * Nn + tx];
  }
  __syncthreads();
  unsigned short* dst = featsT + ((size_t)b * Nn + nt * 64) * Cc + ct * 64;
  int c4 = (t & 15) * 4, n0 = t >> 4;
#pragma unroll
  for (int i = 0; i < 4; i++) {
    int n = i * 16 + n0;
    ushort4 v;
    v.x = f2bf(tile[c4][n]);
    v.y = f2bf(tile[c4 + 1][n]);
    v.z = f2bf(tile[c4 + 2][n]);
    v.w = f2bf(tile[c4 + 3][n]);
    *(ushort4*)&dst[(size_t)n * Cc + c4] = v;
  }
}

// ---------------- fused: R12 body verbatim + s_setprio around MFMA clusters (T5) ---------------
__global__ __launch_bounds__(256, 4) void fused_kernel(
    const unsigned short* __restrict__ featsT, const float4* __restrict__ xyzw,
    const float* __restrict__ new_xyz, const int* __restrict__ idx,
    const unsigned short* __restrict__ W1b, const float* __restrict__ b1e,
    const unsigned short* __restrict__ W2b, const float* __restrict__ b2e,
    float* __restrict__ out) {
  __shared__ unsigned short Xf[64 * 256];  // 32768 B, swizzled feature tile / H tile
  __shared__ unsigned short Xco[64 * 40];  // 5120 B, coord K-chunk
  int t = threadIdx.x;
  int wave = t >> 6, lane = t & 63;
  int lr = lane & 15, kg = lane >> 4;
  int wcol = wave * 64;
  int bm = blockIdx.x;
  int b = bm >> 10;

  // ---- prologue: coord rows + async swizzled gather ----
  if (t < 64) {
    int ci = idx[(size_t)bm * NSAMPLE + t];
    float4 p = xyzw[(size_t)b * Nn + ci];
    unsigned int c01 = (unsigned int)f2bf(p.x - new_xyz[bm * 3])
                     | ((unsigned int)f2bf(p.y - new_xyz[bm * 3 + 1]) << 16);
    unsigned int c2 = (unsigned int)f2bf(p.z - new_xyz[bm * 3 + 2]);
    uint4 v0 = make_uint4(c01, c2, 0u, 0u);
    uint4 z = make_uint4(0u, 0u, 0u, 0u);
    uint4* row = (uint4*)&Xco[t * 40];
    row[0] = v0; row[1] = z; row[2] = z; row[3] = z; row[4] = z;
  }
  {
    int idxr = idx[(size_t)bm * NSAMPLE + wave * 16 + (lane & 15)];
#pragma unroll
    for (int i = 0; i < 8; i++) {
      int j = wave * 8 + i;                       // row pair 2j, 2j+1
      int iv = __shfl(idxr, 2 * i + (lane >> 5));
      int r7 = (2 * j + (lane >> 5)) & 7;
      int cg = (lane & 31) ^ r7;                  // swizzled global chunk (rule #21)
      gload_lds16(featsT + ((size_t)b * Nn + iv) * Cc + cg * 8, &Xf[j * 512]);
    }
  }
  __syncthreads();

  // ---- layer 1: [64x288]x[288x256]; kk 0..7 from Xf (swizzled), kk 8 from Xco ----
  f32x4 acc[4][4];
#pragma unroll
  for (int mi = 0; mi < 4; mi++)
#pragma unroll
    for (int ni = 0; ni < 4; ni++) acc[mi][ni] = (f32x4){0.f, 0.f, 0.f, 0.f};
#pragma unroll
  for (int kk = 0; kk < 9; kk++) {
    bf16x8 w[4];
#pragma unroll
    for (int ni = 0; ni < 4; ni++)
      w[ni] = *(const bf16x8*)&W1b[(size_t)(wcol + ni * 16 + lr) * K1P + kk * 32 + kg * 8];
    bf16x8 a[4];
#pragma unroll
    for (int mi = 0; mi < 4; mi++) {
      int r = mi * 16 + lr;
      if (kk < 8) {
        int cs = ((kk * 4 + kg) ^ (r & 7)) * 8;
        a[mi] = *(const bf16x8*)&Xf[r * 256 + cs];
      } else {
        a[mi] = *(const bf16x8*)&Xco[r * 40 + kg * 8];
      }
    }
    __builtin_amdgcn_s_setprio(1);
#pragma unroll
    for (int mi = 0; mi < 4; mi++)
#pragma unroll
      for (int ni = 0; ni < 4; ni++)
        acc[mi][ni] = __builtin_amdgcn_mfma_f32_16x16x32_bf16(a[mi], w[ni], acc[mi][ni], 0, 0, 0);
    __builtin_amdgcn_s_setprio(0);
  }
  __syncthreads();  // B3: all waves done reading Xf

  // ---- epilogue 1 (thin): bias + relu -> H (aliases Xf, swizzled store) ----
#pragma unroll
  for (int ni = 0; ni < 4; ni++) {
    int o = wcol + ni * 16 + lr;
    float bb = b1e[o];
#pragma unroll
    for (int mi = 0; mi < 4; mi++)
#pragma unroll
      for (int j = 0; j < 4; j++) {
        int r = mi * 16 + kg * 4 + j;
        float h = fmaxf(acc[mi][ni][j] + bb, 0.f);
        Xf[r * 256 + ((((o >> 3) ^ (r & 7)) << 3) + (o & 7))] = f2bf(h);
      }
  }
  __syncthreads();  // B4: H visible

  // ---- layer 2: [64x256]x[256x256] from H (same swizzle) ----
#pragma unroll
  for (int mi = 0; mi < 4; mi++)
#pragma unroll
    for (int ni = 0; ni < 4; ni++) acc[mi][ni] = (f32x4){0.f, 0.f, 0.f, 0.f};
#pragma unroll
  for (int kk = 0; kk < 8; kk++) {
    bf16x8 w[4];
#pragma unroll
    for (int ni = 0; ni < 4; ni++)
      w[ni] = *(const bf16x8*)&W2b[(size_t)(wcol + ni * 16 + lr) * 256 + kk * 32 + kg * 8];
    bf16x8 a[4];
#pragma unroll
    for (int mi = 0; mi < 4; mi++) {
      int r = mi * 16 + lr;
      int cs = ((kk * 4 + kg) ^ (r & 7)) * 8;
      a[mi] = *(const bf16x8*)&Xf[r * 256 + cs];
    }
    __builtin_amdgcn_s_setprio(1);
#pragma unroll
    for (int mi = 0; mi < 4; mi++)
#pragma unroll
      for (int ni = 0; ni < 4; ni++)
        acc[mi][ni] = __builtin_amdgcn_mfma_f32_16x16x32_bf16(a[mi], w[ni], acc[mi][ni], 0, 0, 0);
    __builtin_amdgcn_s_setprio(0);
  }
  // ---- epilogue 2: bias + relu + max over 64 samples -> out[b][o][m] ----
  {
    int m = bm & (Mm - 1);
#pragma unroll
    for (int ni = 0; ni < 4; ni++) {
      float bv = b2e[wcol + ni * 16 + lr];
      float v = 0.f;  // relu(max) == max(relu)
#pragma unroll
      for (int mi = 0; mi < 4; mi++)
#pragma unroll
        for (int j = 0; j < 4; j++) v = fmaxf(v, acc[mi][ni][j] + bv);
      v = fmaxf(v, __shfl_xor(v, 16));
      v = fmaxf(v, __shfl_xor(v, 32));
      if (kg == 0)
        out[((size_t)b * 256 + wcol + ni * 16 + lr) * Mm + m] = v;
    }
  }
}

extern "C" void kernel_launch(void* const* d_in, const int* in_sizes, int n_in,
                              void* d_out, int out_size, void* d_ws, size_t ws_size,
                              hipStream_t stream) {
  (void)in_sizes; (void)n_in; (void)out_size; (void)ws_size;
  const float* xyz     = (const float*)d_in[0];
  const float* new_xyz = (const float*)d_in[1];
  const float* feats   = (const float*)d_in[2];
  const float* W1 = (const float*)d_in[3];
  const float* b1 = (const float*)d_in[4];
  const float* g1 = (const float*)d_in[5];
  const float* be1 = (const float*)d_in[6];
  const float* m1 = (const float*)d_in[7];
  const float* v1 = (const float*)d_in[8];
  const float* W2 = (const float*)d_in[9];
  const float* b2 = (const float*)d_in[10];
  const float* g2 = (const float*)d_in[11];
  const float* be2 = (const float*)d_in[12];
  const float* m2 = (const float*)d_in[13];
  const float* v2 = (const float*)d_in[14];
  float* out = (float*)d_out;

  char* ws = (char*)d_ws;
  unsigned short* W1b   = (unsigned short*)(ws + 0);         // 147456 B ([256][288])
  unsigned short* W2b   = (unsigned short*)(ws + 147456);    // 131072 B
  float*          b1e   = (float*)(ws + 278528);             // 1024 B
  float*          b2e   = (float*)(ws + 279552);             // 1024 B
  float4*         xyzw  = (float4*)(ws + 280576);            // 1048576 B
  unsigned short* featsT= (unsigned short*)(ws + 1329152);   // 33554432 B
  int*            idx   = (int*)(ws + 34883584);             // 1048576 B

  prep_kernel<<<(256 * K1P + 255) / 256, 256, 0, stream>>>(
      W1, b1, g1, be1, m1, v1, W2, b2, g2, be2, m2, v2, W1b, b1e, W2b, b2e);
  xyzw_kernel<<<(Bb * Nn) / 256, 256, 0, stream>>>(xyz, xyzw);
  featsT_ballq_kernel<<<1024 + Bb * (Nn / 64) * (Cc / 64), 256, 0, stream>>>(
      feats, featsT, xyzw, new_xyz, idx);
  fused_kernel<<<Bb * Mm, 256, 0, stream>>>(featsT, xyzw, new_xyz, idx,
                                            W1b, b1e, W2b, b2e, out);
}

// Round 14
// 175.822 us; speedup vs baseline: 1.7397x; 1.2073x over previous
//
#include <hip/hip_runtime.h>
#include <stdint.h>

typedef __bf16 bf16x8 __attribute__((ext_vector_type(8)));
typedef float f32x4 __attribute__((ext_vector_type(4)));

#define NSAMPLE 64
static constexpr int Bb = 4, Nn = 16384, Mm = 1024, Cc = 256;
static constexpr int K1P = 288;   // layer-1 K: 256 features + 3 coords + pad (9 x 32)

__device__ __forceinline__ unsigned short f2bf(float f) {
  unsigned int u = __builtin_bit_cast(unsigned int, f);
  u = u + 0x7fffu + ((u >> 16) & 1u);
  return (unsigned short)(u >> 16);
}

// async global->LDS, 16B per lane; LDS dest = wave-uniform base + lane*16
__device__ __forceinline__ void gload_lds16(const void* g, void* lds) {
  __builtin_amdgcn_global_load_lds(
      (const __attribute__((address_space(1))) uint32_t*)g,
      (__attribute__((address_space(3))) uint32_t*)lds, 16, 0, 0);
}

// ---- prep + xyzw merged at BLOCK level: blocks 0..287 prep (R1-verbatim body),
// ---- blocks 288..543 xyzw (R1-verbatim body). Independent outputs; no thread-guard merge.
__global__ void prep_xyzw_kernel(const float* __restrict__ W1, const float* __restrict__ b1,
                                 const float* __restrict__ g1, const float* __restrict__ be1,
                                 const float* __restrict__ m1, const float* __restrict__ v1,
                                 const float* __restrict__ W2, const float* __restrict__ b2,
                                 const float* __restrict__ g2, const float* __restrict__ be2,
                                 const float* __restrict__ m2, const float* __restrict__ v2,
                                 const float* __restrict__ xyz,
                                 unsigned short* __restrict__ W1b, float* __restrict__ b1e,
                                 unsigned short* __restrict__ W2b, float* __restrict__ b2e,
                                 float4* __restrict__ xyzw) {
  int bx = blockIdx.x;
  if (bx < 288) {
    // ---------------- prep body (R1 verbatim, t from local block range) ----------------
    int t = bx * 256 + threadIdx.x;
    if (t < 256 * K1P) {
      int o = t / K1P, k = t - o * K1P;
      float s = g1[o] / sqrtf(v1[o] + 1e-5f);
      float w = 0.f;
      if (k < 256) w = W1[o * 259 + 3 + k];
      else if (k < 259) w = W1[o * 259 + (k - 256)];
      W1b[t] = f2bf(w * s);
    }
    if (t < 256 * 256) {
      int o = t >> 8;
      float s = g2[o] / sqrtf(v2[o] + 1e-5f);
      W2b[t] = f2bf(W2[t] * s);
    }
    if (t < 256) {
      float s1 = g1[t] / sqrtf(v1[t] + 1e-5f);
      b1e[t] = s1 * (b1[t] - m1[t]) + be1[t];
      float s2 = g2[t] / sqrtf(v2[t] + 1e-5f);
      b2e[t] = s2 * (b2[t] - m2[t]) + be2[t];
    }
    return;
  }
  // ---------------- xyzw body (R1 verbatim, t from local block range) ----------------
  int t = (bx - 288) * 256 + threadIdx.x;  // 0..65535
  float x = xyz[t * 3], y = xyz[t * 3 + 1], z = xyz[t * 3 + 2];
  float pp = __fadd_rn(__fadd_rn(__fmul_rn(x, x), __fmul_rn(y, y)), __fmul_rn(z, z));
  xyzw[t] = make_float4(x, y, z, pp);
}

// ---- featsT + ballq merged at BLOCK level. blocks 0..4095: ballq, ONE query/block with the
// ---- scan split across 4 waves (wave w scans n in [w*4096,(w+1)*4096), 64 chunks each);
// ---- per-wave ordered hit lists merged by threads 0..63. blocks 4096..8191: featsT verbatim.
// Correctness of split ballq: global first-64-in-order = concat of per-wave ordered hit lists
// by wave id. Wave w stores its first 64 hits + exact-ish count cnt_w (early break at >=64 is
// safe: any cnt_w>=64 makes later waves' offsets >=64 (unused) and cc=64 regardless; padding
// (tot<64) only occurs when no wave hit the cap, so counts are exact there).
__global__ void featsT_ballq_kernel(const float* __restrict__ feats,
                                    unsigned short* __restrict__ featsT,
                                    const float4* __restrict__ xyzw,
                                    const float* __restrict__ new_xyz,
                                    int* __restrict__ idx) {
  __shared__ float tile[64][65];
  __shared__ int wl[4][64];
  __shared__ int wcnt[4];
  int bx = blockIdx.x;
  int t = threadIdx.x;
  if (bx < 4096) {
    const float r2 = (float)(0.08 * 0.08);
    int bm = bx;
    int lane = t & 63, w = t >> 6;
    int b = bm >> 10;
    float qx = new_xyz[bm * 3], qy = new_xyz[bm * 3 + 1], qz = new_xyz[bm * 3 + 2];
    float qq = __fadd_rn(__fadd_rn(__fmul_rn(qx, qx), __fmul_rn(qy, qy)), __fmul_rn(qz, qz));
    const float4* P = xyzw + (size_t)b * Nn + w * 4096;
    int cnt = 0;
    for (int n0 = 0; n0 < 4096; n0 += 64) {
      float4 p = P[n0 + lane];
      float dt = __fadd_rn(__fadd_rn(__fmul_rn(qx, p.x), __fmul_rn(qy, p.y)), __fmul_rn(qz, p.z));
      float d2 = __fsub_rn(__fadd_rn(qq, p.w), __fmul_rn(2.f, dt));
      bool valid = d2 < r2;
      unsigned long long mask = __ballot(valid);
      if (mask) {
        if (valid) {
          int pos = cnt + __popcll(mask & ((1ull << lane) - 1ull));
          if (pos < NSAMPLE) wl[w][pos] = w * 4096 + n0 + lane;
        }
        cnt += (int)__popcll(mask);
        if (cnt >= NSAMPLE) break;
      }
    }
    if (lane == 0) wcnt[w] = cnt;
    __syncthreads();
    if (t < NSAMPLE) {
      int c0 = wcnt[0], c1 = wcnt[1], c2 = wcnt[2], c3 = wcnt[3];
      int tot = c0 + c1 + c2 + c3;
      int cc = tot < NSAMPLE ? tot : NSAMPLE;
      int v;
      if (t < cc) {
        if (t < c0) v = wl[0][t];
        else if (t < c0 + c1) v = wl[1][t - c0];
        else if (t < c0 + c1 + c2) v = wl[2][t - c0 - c1];
        else v = wl[3][t - c0 - c1 - c2];
      } else {
        v = (c0 > 0) ? wl[0][0] : (c1 > 0) ? wl[1][0] : (c2 > 0) ? wl[2][0] : (c3 > 0) ? wl[3][0] : 0;
      }
      idx[(size_t)bm * NSAMPLE + t] = v;
    }
    return;
  }
  // ---------------- featsT — R8 verbatim body ----------------
  int fb = bx - 4096;             // 0..4095
  int b = fb >> 10;
  int rem = fb & 1023;
  int nt = rem >> 2, ct = rem & 3;
  int tx = t & 63, ty = t >> 6;
  const float* src = feats + ((size_t)b * Cc + ct * 64) * Nn + nt * 64;
#pragma unroll
  for (int i = 0; i < 16; i++) {
    int c = i * 4 + ty;
    tile[c][tx] = src[(size_t)c * Nn + tx];
  }
  __syncthreads();
  unsigned short* dst = featsT + ((size_t)b * Nn + nt * 64) * Cc + ct * 64;
  int c4 = (t & 15) * 4, n0 = t >> 4;
#pragma unroll
  for (int i = 0; i < 4; i++) {
    int n = i * 16 + n0;
    ushort4 v;
    v.x = f2bf(tile[c4][n]);
    v.y = f2bf(tile[c4 + 1][n]);
    v.z = f2bf(tile[c4 + 2][n]);
    v.w = f2bf(tile[c4 + 3][n]);
    *(ushort4*)&dst[(size_t)n * Cc + c4] = v;
  }
}

// ---------------- fused: R13 verbatim ----------------
__global__ __launch_bounds__(256, 4) void fused_kernel(
    const unsigned short* __restrict__ featsT, const float4* __restrict__ xyzw,
    const float* __restrict__ new_xyz, const int* __restrict__ idx,
    const unsigned short* __restrict__ W1b, const float* __restrict__ b1e,
    const unsigned short* __restrict__ W2b, const float* __restrict__ b2e,
    float* __restrict__ out) {
  __shared__ unsigned short Xf[64 * 256];  // 32768 B, swizzled feature tile / H tile
  __shared__ unsigned short Xco[64 * 40];  // 5120 B, coord K-chunk
  int t = threadIdx.x;
  int wave = t >> 6, lane = t & 63;
  int lr = lane & 15, kg = lane >> 4;
  int wcol = wave * 64;
  int bm = blockIdx.x;
  int b = bm >> 10;

  if (t < 64) {
    int ci = idx[(size_t)bm * NSAMPLE + t];
    float4 p = xyzw[(size_t)b * Nn + ci];
    unsigned int c01 = (unsigned int)f2bf(p.x - new_xyz[bm * 3])
                     | ((unsigned int)f2bf(p.y - new_xyz[bm * 3 + 1]) << 16);
    unsigned int c2 = (unsigned int)f2bf(p.z - new_xyz[bm * 3 + 2]);
    uint4 v0 = make_uint4(c01, c2, 0u, 0u);
    uint4 z = make_uint4(0u, 0u, 0u, 0u);
    uint4* row = (uint4*)&Xco[t * 40];
    row[0] = v0; row[1] = z; row[2] = z; row[3] = z; row[4] = z;
  }
  {
    int idxr = idx[(size_t)bm * NSAMPLE + wave * 16 + (lane & 15)];
#pragma unroll
    for (int i = 0; i < 8; i++) {
      int j = wave * 8 + i;                       // row pair 2j, 2j+1
      int iv = __shfl(idxr, 2 * i + (lane >> 5));
      int r7 = (2 * j + (lane >> 5)) & 7;
      int cg = (lane & 31) ^ r7;                  // swizzled global chunk (rule #21)
      gload_lds16(featsT + ((size_t)b * Nn + iv) * Cc + cg * 8, &Xf[j * 512]);
    }
  }
  __syncthreads();

  f32x4 acc[4][4];
#pragma unroll
  for (int mi = 0; mi < 4; mi++)
#pragma unroll
    for (int ni = 0; ni < 4; ni++) acc[mi][ni] = (f32x4){0.f, 0.f, 0.f, 0.f};
#pragma unroll
  for (int kk = 0; kk < 9; kk++) {
    bf16x8 w[4];
#pragma unroll
    for (int ni = 0; ni < 4; ni++)
      w[ni] = *(const bf16x8*)&W1b[(size_t)(wcol + ni * 16 + lr) * K1P + kk * 32 + kg * 8];
    bf16x8 a[4];
#pragma unroll
    for (int mi = 0; mi < 4; mi++) {
      int r = mi * 16 + lr;
      if (kk < 8) {
        int cs = ((kk * 4 + kg) ^ (r & 7)) * 8;
        a[mi] = *(const bf16x8*)&Xf[r * 256 + cs];
      } else {
        a[mi] = *(const bf16x8*)&Xco[r * 40 + kg * 8];
      }
    }
    __builtin_amdgcn_s_setprio(1);
#pragma unroll
    for (int mi = 0; mi < 4; mi++)
#pragma unroll
      for (int ni = 0; ni < 4; ni++)
        acc[mi][ni] = __builtin_amdgcn_mfma_f32_16x16x32_bf16(a[mi], w[ni], acc[mi][ni], 0, 0, 0);
    __builtin_amdgcn_s_setprio(0);
  }
  __syncthreads();  // B3

#pragma unroll
  for (int ni = 0; ni < 4; ni++) {
    int o = wcol + ni * 16 + lr;
    float bb = b1e[o];
#pragma unroll
    for (int mi = 0; mi < 4; mi++)
#pragma unroll
      for (int j = 0; j < 4; j++) {
        int r = mi * 16 + kg * 4 + j;
        float h = fmaxf(acc[mi][ni][j] + bb, 0.f);
        Xf[r * 256 + ((((o >> 3) ^ (r & 7)) << 3) + (o & 7))] = f2bf(h);
      }
  }
  __syncthreads();  // B4

#pragma unroll
  for (int mi = 0; mi < 4; mi++)
#pragma unroll
    for (int ni = 0; ni < 4; ni++) acc[mi][ni] = (f32x4){0.f, 0.f, 0.f, 0.f};
#pragma unroll
  for (int kk = 0; kk < 8; kk++) {
    bf16x8 w[4];
#pragma unroll
    for (int ni = 0; ni < 4; ni++)
      w[ni] = *(const bf16x8*)&W2b[(size_t)(wcol + ni * 16 + lr) * 256 + kk * 32 + kg * 8];
    bf16x8 a[4];
#pragma unroll
    for (int mi = 0; mi < 4; mi++) {
      int r = mi * 16 + lr;
      int cs = ((kk * 4 + kg) ^ (r & 7)) * 8;
      a[mi] = *(const bf16x8*)&Xf[r * 256 + cs];
    }
    __builtin_amdgcn_s_setprio(1);
#pragma unroll
    for (int mi = 0; mi < 4; mi++)
#pragma unroll
      for (int ni = 0; ni < 4; ni++)
        acc[mi][ni] = __builtin_amdgcn_mfma_f32_16x16x32_bf16(a[mi], w[ni], acc[mi][ni], 0, 0, 0);
    __builtin_amdgcn_s_setprio(0);
  }
  {
    int m = bm & (Mm - 1);
#pragma unroll
    for (int ni = 0; ni < 4; ni++) {
      float bv = b2e[wcol + ni * 16 + lr];
      float v = 0.f;  // relu(max) == max(relu)
#pragma unroll
      for (int mi = 0; mi < 4; mi++)
#pragma unroll
        for (int j = 0; j < 4; j++) v = fmaxf(v, acc[mi][ni][j] + bv);
      v = fmaxf(v, __shfl_xor(v, 16));
      v = fmaxf(v, __shfl_xor(v, 32));
      if (kg == 0)
        out[((size_t)b * 256 + wcol + ni * 16 + lr) * Mm + m] = v;
    }
  }
}

extern "C" void kernel_launch(void* const* d_in, const int* in_sizes, int n_in,
                              void* d_out, int out_size, void* d_ws, size_t ws_size,
                              hipStream_t stream) {
  (void)in_sizes; (void)n_in; (void)out_size; (void)ws_size;
  const float* xyz     = (const float*)d_in[0];
  const float* new_xyz = (const float*)d_in[1];
  const float* feats   = (const float*)d_in[2];
  const float* W1 = (const float*)d_in[3];
  const float* b1 = (const float*)d_in[4];
  const float* g1 = (const float*)d_in[5];
  const float* be1 = (const float*)d_in[6];
  const float* m1 = (const float*)d_in[7];
  const float* v1 = (const float*)d_in[8];
  const float* W2 = (const float*)d_in[9];
  const float* b2 = (const float*)d_in[10];
  const float* g2 = (const float*)d_in[11];
  const float* be2 = (const float*)d_in[12];
  const float* m2 = (const float*)d_in[13];
  const float* v2 = (const float*)d_in[14];
  float* out = (float*)d_out;

  char* ws = (char*)d_ws;
  unsigned short* W1b   = (unsigned short*)(ws + 0);         // 147456 B ([256][288])
  unsigned short* W2b   = (unsigned short*)(ws + 147456);    // 131072 B
  float*          b1e   = (float*)(ws + 278528);             // 1024 B
  float*          b2e   = (float*)(ws + 279552);             // 1024 B
  float4*         xyzw  = (float4*)(ws + 280576);            // 1048576 B
  unsigned short* featsT= (unsigned short*)(ws + 1329152);   // 33554432 B
  int*            idx   = (int*)(ws + 34883584);             // 1048576 B

  prep_xyzw_kernel<<<288 + 256, 256, 0, stream>>>(
      W1, b1, g1, be1, m1, v1, W2, b2, g2, be2, m2, v2, xyz, W1b, b1e, W2b, b2e, xyzw);
  featsT_ballq_kernel<<<4096 + 4096, 256, 0, stream>>>(feats, featsT, xyzw, new_xyz, idx);
  fused_kernel<<<Bb * Mm, 256, 0, stream>>>(featsT, xyzw, new_xyz, idx,
                                            W1b, b1e, W2b, b2e, out);
}